// Round 5
// baseline (251.827 us; speedup 1.0000x reference)
//
#include <hip/hip_runtime.h>

typedef __attribute__((ext_vector_type(8))) short short8;
typedef __attribute__((ext_vector_type(4))) float f32x4;

static __device__ __forceinline__ unsigned short f2b(float f) {
  union { float f; unsigned int u; } v; v.f = f;
  unsigned int u = v.u;
  unsigned int r = (u + 0x7FFFu + ((u >> 16) & 1u)) >> 16;
  return (unsigned short)r;
}
static __device__ __forceinline__ float b2f(unsigned short u) {
  union { unsigned int u; float f; } v; v.u = ((unsigned int)u) << 16;
  return v.f;
}

// ---------------------------------------------------------------------------
// K0: cast feature table (in_core | aux | zero row) and weight to bf16
// ---------------------------------------------------------------------------
__global__ __launch_bounds__(256) void prep_kernel(
    const float* __restrict__ core, const float* __restrict__ aux,
    const float* __restrict__ wgt,
    unsigned short* __restrict__ tab, unsigned short* __restrict__ wB)
{
  const long TAB = 12001L * 256;   // 3072256
  const long WN  = 256L * 2304;    // 589824
  long i = ((long)blockIdx.x * 256 + threadIdx.x) * 4;
  float4 v;
  unsigned short* dst;
  if (i < TAB) {
    long row = i >> 8;
    if (row < 8000)        v = *(const float4*)(core + i);
    else if (row < 12000)  v = *(const float4*)(aux + (i - 8000L * 256));
    else                   v = make_float4(0.f, 0.f, 0.f, 0.f);
    dst = tab + i;
  } else {
    long j = i - TAB;
    if (j >= WN) return;
    v = *(const float4*)(wgt + j);
    dst = wB + j;
  }
  ushort4 o = make_ushort4(f2b(v.x), f2b(v.y), f2b(v.z), f2b(v.w));
  *(ushort4*)dst = o;
}

// ---------------------------------------------------------------------------
// K1: projections (63 dots per row, f32) -> gids + combined weights
// NOTE reference's (non-standard) bilinear weights:
//   w[g] = delta[x_ids[g]] * (1-delta)[y_ids[g]], x_ids=[1,0,1,0], y_ids=[1,1,0,0]
//   -> factor1 = gx ? dx : dy ; factor2 = gy ? (1-dx) : (1-dy)
// ---------------------------------------------------------------------------
__global__ __launch_bounds__(256) void proj_kernel(
    const float* __restrict__ core,
    const float* __restrict__ off_w, const float* __restrict__ off_b,
    const float* __restrict__ pw_w,  const float* __restrict__ pw_b,
    const float* __restrict__ mw_w,  const float* __restrict__ mw_b,
    const int* __restrict__ id_map, const int* __restrict__ roi_ids,
    const int* __restrict__ pos_ids,
    int* __restrict__ gids, float* __restrict__ wts)
{
  __shared__ float dots[32][64];
  const int tid  = threadIdx.x;
  const int lane = tid & 63;
  const int wv   = tid >> 6;
  const int nbase = blockIdx.x * 32 + wv * 8;

  float acc[8] = {0.f,0.f,0.f,0.f,0.f,0.f,0.f,0.f};
  if (lane < 63) {
    const float* wr; float bb;
    if (lane < 36)      { wr = off_w + lane * 256;       bb = off_b[lane]; }
    else if (lane < 54) { wr = pw_w + (lane - 36) * 256; bb = pw_b[lane - 36]; }
    else                { wr = mw_w + (lane - 54) * 256; bb = mw_b[lane - 54]; }
    const float4* w4 = (const float4*)wr;
    #pragma unroll 4
    for (int i = 0; i < 64; ++i) {
      const float4 w = w4[i];
      #pragma unroll
      for (int r = 0; r < 8; ++r) {
        const float4 x = *(const float4*)(core + (long)(nbase + r) * 256 + i * 4);
        acc[r] += w.x * x.x + w.y * x.y + w.z * x.z + w.w * x.w;
      }
    }
    #pragma unroll
    for (int r = 0; r < 8; ++r) acc[r] += bb;
  }
  #pragma unroll
  for (int r = 0; r < 8; ++r) dots[wv * 8 + r][lane] = acc[r];
  __syncthreads();

  #pragma unroll
  for (int round = 0; round < 3; ++round) {
    int task = round * 256 + tid;
    if (task < 576) {
      int nl = task / 18;
      int kp = task - nl * 18;
      int k = kp >> 1, p = kp & 1;
      int n = blockIdx.x * 32 + nl;
      float x = dots[nl][k*4 + p*2 + 0] + (float)pos_ids[n*2 + 0];
      float y = dots[nl][k*4 + p*2 + 1] + (float)pos_ids[n*2 + 1];
      float fx = floorf(x), fy = floorf(y);
      float dx = x - fx, dy = y - fy;
      int bx = (int)fx, by = (int)fy;
      float l0 = dots[nl][36 + k*2], l1 = dots[nl][36 + k*2 + 1];
      float mmax = fmaxf(l0, l1);
      float e0 = __expf(l0 - mmax), e1 = __expf(l1 - mmax);
      float pwv = (p ? e1 : e0) / (e0 + e1);
      float mwv = 1.f / (1.f + __expf(-dots[nl][54 + k]));
      float wb  = pwv * mwv;
      const int* imap = id_map + roi_ids[n] * 4096;
      int base = ((n * 9 + k) * 2 + p) * 4;
      #pragma unroll
      for (int g = 0; g < 4; ++g) {
        int gx = g & 1, gy = g >> 1;
        int cx = bx + gx, cy = by + gy;
        bool pad = ((cx | cy) < 0) | (cx >= 64) | (cy >= 64);
        int cxc = min(max(cx, 0), 63), cyc = min(max(cy, 0), 63);
        int gid = pad ? 12000 : imap[cyc * 64 + cxc];
        float f1 = gx ? dx : dy;
        float f2 = gy ? (1.f - dx) : (1.f - dy);
        gids[base + g] = gid;
        wts[base + g]  = wb * f1 * f2;
      }
    }
  }
}

// ---------------------------------------------------------------------------
// K2: fused gather + GEMM.  out[8000,256] = sampled @ W^T + bias, where
// sampled[n, k*256+c] = sum_j wts[n,k,j] * tab[gids[n,k,j], c]  (never stored)
// grid 250 x (512 thr = 8 waves); BM=32, BN=256, BK=64, 36 K-steps (9 taps x 4)
// Software-pipelined: next step's gather/B loads issued before MFMA phase.
// ---------------------------------------------------------------------------
__global__ __launch_bounds__(512) void gg_kernel(
    const unsigned short* __restrict__ tab,
    const unsigned short* __restrict__ W,
    const int* __restrict__ gids, const float* __restrict__ wts,
    const float* __restrict__ bias, float* __restrict__ out)
{
  __shared__ __align__(16) unsigned short As[32][72];
  __shared__ __align__(16) unsigned short Bs[256][72];

  const int t    = threadIdx.x;
  const int m0   = blockIdx.x * 32;
  const int row  = t >> 4;        // 0..31  (gather role)
  const int q    = t & 15;        // 0..15  -> channels q*4..q*4+3
  const int bn   = t >> 1;        // 0..255 (B-stage role)
  const int bh   = t & 1;         // 0..1
  const int lane = t & 63;
  const int wv   = t >> 6;        // 0..7
  const int wr   = wv >> 2;       // 0..1 (M)
  const int wc   = wv & 3;        // 0..3 (N)

  f32x4 acc[4] = {};

  const long grow = (long)(m0 + row) * 72;
  int   gid[8]; float w[8];
  ushort4 tv[8];
  uint4   bv[4];

  // ---- prologue: tap 0, kt 0
  #pragma unroll
  for (int j = 0; j < 8; ++j) { gid[j] = gids[grow + j]; w[j] = wts[grow + j]; }
  {
    const int c = q * 4;
    #pragma unroll
    for (int j = 0; j < 8; ++j)
      tv[j] = *(const ushort4*)(tab + (long)gid[j] * 256 + c);
    #pragma unroll
    for (int u = 0; u < 4; ++u)
      bv[u] = *(const uint4*)(W + (long)bn * 2304 + bh * 32 + u * 8);
  }

  for (int kt = 0; kt < 36; ++kt) {
    __syncthreads();   // previous MFMA phase done reading LDS
    // ---- commit staged data (waits on the in-flight loads)
    {
      float a0 = 0.f, a1 = 0.f, a2 = 0.f, a3 = 0.f;
      #pragma unroll
      for (int j = 0; j < 8; ++j) {
        a0 += w[j] * b2f(tv[j].x); a1 += w[j] * b2f(tv[j].y);
        a2 += w[j] * b2f(tv[j].z); a3 += w[j] * b2f(tv[j].w);
      }
      *(ushort4*)&As[row][q * 4] = make_ushort4(f2b(a0), f2b(a1), f2b(a2), f2b(a3));
      #pragma unroll
      for (int u = 0; u < 4; ++u)
        *(uint4*)&Bs[bn][bh * 32 + u * 8] = bv[u];
    }
    __syncthreads();
    // ---- issue loads for kt+1 (fly under the MFMA phase)
    const int nkt = kt + 1;
    if (nkt < 36) {
      if ((nkt & 3) == 0) {
        const int tap = nkt >> 2;
        #pragma unroll
        for (int j = 0; j < 8; ++j) {
          gid[j] = gids[grow + tap * 8 + j];
          // w[j] for the new tap is loaded AFTER it was consumed above next iter?
          // NOTE: w[] is consumed in the commit of kt (done above), safe to reload.
          w[j] = wts[grow + tap * 8 + j];
        }
      }
      const int c = (nkt & 3) * 64 + q * 4;
      #pragma unroll
      for (int j = 0; j < 8; ++j)
        tv[j] = *(const ushort4*)(tab + (long)gid[j] * 256 + c);
      #pragma unroll
      for (int u = 0; u < 4; ++u)
        bv[u] = *(const uint4*)(W + (long)bn * 2304 + nkt * 64 + bh * 32 + u * 8);
    }
    // ---- MFMA phase
    #pragma unroll
    for (int kc = 0; kc < 2; ++kc) {
      const int kk = kc * 32 + (lane >> 4) * 8;
      const short8 af = *(const short8*)&As[wr * 16 + (lane & 15)][kk];
      #pragma unroll
      for (int nf = 0; nf < 4; ++nf) {
        const short8 bf = *(const short8*)&Bs[wc * 64 + nf * 16 + (lane & 15)][kk];
        acc[nf] = __builtin_amdgcn_mfma_f32_16x16x32_bf16(af, bf, acc[nf], 0, 0, 0);
      }
    }
  }

  // ---- epilogue
  const int orow = m0 + wr * 16 + (lane >> 4) * 4;
  #pragma unroll
  for (int nf = 0; nf < 4; ++nf) {
    const int col = wc * 64 + nf * 16 + (lane & 15);
    const float bs = bias[col];
    #pragma unroll
    for (int r = 0; r < 4; ++r)
      out[(long)(orow + r) * 256 + col] = acc[nf][r] + bs;
  }
}

// ---------------------------------------------------------------------------
extern "C" void kernel_launch(void* const* d_in, const int* in_sizes, int n_in,
                              void* d_out, int out_size, void* d_ws, size_t ws_size,
                              hipStream_t stream)
{
  const float* core   = (const float*)d_in[0];
  const float* aux    = (const float*)d_in[1];
  const float* off_w  = (const float*)d_in[2];
  const float* off_b  = (const float*)d_in[3];
  const float* pw_w   = (const float*)d_in[4];
  const float* pw_b   = (const float*)d_in[5];
  const float* mw_w   = (const float*)d_in[6];
  const float* mw_b   = (const float*)d_in[7];
  const float* wgt    = (const float*)d_in[8];
  const float* bias   = (const float*)d_in[9];
  const int* id_map   = (const int*)d_in[10];
  const int* roi_ids  = (const int*)d_in[11];
  const int* pos_ids  = (const int*)d_in[12];
  char* ws = (char*)d_ws;

  unsigned short* tab = (unsigned short*)(ws);              // 12001*256*2 = 6,144,512
  unsigned short* wB  = (unsigned short*)(ws + 6144512);    // 256*2304*2  = 1,179,648
  int*            gd  = (int*)           (ws + 7324160);    // 8000*72*4   = 2,304,000
  float*          wt  = (float*)         (ws + 9628160);    // 8000*72*4   = 2,304,000
  float* out = (float*)d_out;

  hipLaunchKernelGGL(prep_kernel, dim3(3577), dim3(256), 0, stream,
                     core, aux, wgt, tab, wB);
  hipLaunchKernelGGL(proj_kernel, dim3(250), dim3(256), 0, stream,
                     core, off_w, off_b, pw_w, pw_b, mw_w, mw_b,
                     id_map, roi_ids, pos_ids, gd, wt);
  hipLaunchKernelGGL(gg_kernel, dim3(250), dim3(512), 0, stream,
                     tab, wB, gd, wt, bias, out);
}

// Round 7
// 224.523 us; speedup vs baseline: 1.1216x; 1.1216x over previous
//
#include <hip/hip_runtime.h>

typedef __attribute__((ext_vector_type(8))) short short8;
typedef __attribute__((ext_vector_type(4))) float f32x4;

static __device__ __forceinline__ unsigned short f2b(float f) {
  union { float f; unsigned int u; } v; v.f = f;
  unsigned int u = v.u;
  unsigned int r = (u + 0x7FFFu + ((u >> 16) & 1u)) >> 16;
  return (unsigned short)r;
}
static __device__ __forceinline__ float b2f(unsigned short u) {
  union { unsigned int u; float f; } v; v.u = ((unsigned int)u) << 16;
  return v.f;
}

// ---------------------------------------------------------------------------
// K0: prep (blocks 0..3576) + proj (blocks 3577..3826) merged.
// prep: cast feature table (core|aux|zero) and weight to bf16.
// proj: 63 f32 dots per row -> gids + combined weights.
// Reference's NON-standard bilinear (discontinuous across floor boundaries —
// must stay f32): w[g] = delta[x_ids[g]]*(1-delta)[y_ids[g]],
// x_ids=[1,0,1,0], y_ids=[1,1,0,0] -> f1 = gx?dx:dy ; f2 = gy?(1-dx):(1-dy)
// ---------------------------------------------------------------------------
__global__ __launch_bounds__(256) void setup_kernel(
    const float* __restrict__ core, const float* __restrict__ aux,
    const float* __restrict__ wgt,
    const float* __restrict__ off_w, const float* __restrict__ off_b,
    const float* __restrict__ pw_w,  const float* __restrict__ pw_b,
    const float* __restrict__ mw_w,  const float* __restrict__ mw_b,
    const int* __restrict__ id_map, const int* __restrict__ roi_ids,
    const int* __restrict__ pos_ids,
    unsigned short* __restrict__ tab, unsigned short* __restrict__ wB,
    int* __restrict__ gids, float* __restrict__ wts)
{
  __shared__ float dots[32][64];
  if (blockIdx.x < 3577) {
    // ---------------- prep ----------------
    const long TAB = 12001L * 256;
    const long WN  = 256L * 2304;
    long i = ((long)blockIdx.x * 256 + threadIdx.x) * 4;
    float4 v;
    unsigned short* dst;
    if (i < TAB) {
      long row = i >> 8;
      if (row < 8000)        v = *(const float4*)(core + i);
      else if (row < 12000)  v = *(const float4*)(aux + (i - 8000L * 256));
      else                   v = make_float4(0.f, 0.f, 0.f, 0.f);
      dst = tab + i;
    } else {
      long j = i - TAB;
      if (j >= WN) return;
      v = *(const float4*)(wgt + j);
      dst = wB + j;
    }
    *(ushort4*)dst = make_ushort4(f2b(v.x), f2b(v.y), f2b(v.z), f2b(v.w));
    return;
  }
  // ---------------- proj ----------------
  const int bid  = blockIdx.x - 3577;
  const int tid  = threadIdx.x;
  const int lane = tid & 63;
  const int wv   = tid >> 6;
  const int nbase = bid * 32 + wv * 8;

  float acc[8] = {0.f,0.f,0.f,0.f,0.f,0.f,0.f,0.f};
  if (lane < 63) {
    const float* wr; float bb;
    if (lane < 36)      { wr = off_w + lane * 256;       bb = off_b[lane]; }
    else if (lane < 54) { wr = pw_w + (lane - 36) * 256; bb = pw_b[lane - 36]; }
    else                { wr = mw_w + (lane - 54) * 256; bb = mw_b[lane - 54]; }
    const float4* w4 = (const float4*)wr;
    #pragma unroll 4
    for (int i = 0; i < 64; ++i) {
      const float4 w = w4[i];
      #pragma unroll
      for (int r = 0; r < 8; ++r) {
        const float4 x = *(const float4*)(core + (long)(nbase + r) * 256 + i * 4);
        acc[r] += w.x * x.x + w.y * x.y + w.z * x.z + w.w * x.w;
      }
    }
    #pragma unroll
    for (int r = 0; r < 8; ++r) acc[r] += bb;
  }
  #pragma unroll
  for (int r = 0; r < 8; ++r) dots[wv * 8 + r][lane] = acc[r];
  __syncthreads();

  #pragma unroll
  for (int round = 0; round < 3; ++round) {
    int task = round * 256 + tid;
    if (task < 576) {
      int nl = task / 18;
      int kp = task - nl * 18;
      int k = kp >> 1, p = kp & 1;
      int n = bid * 32 + nl;
      float x = dots[nl][k*4 + p*2 + 0] + (float)pos_ids[n*2 + 0];
      float y = dots[nl][k*4 + p*2 + 1] + (float)pos_ids[n*2 + 1];
      float fx = floorf(x), fy = floorf(y);
      float dx = x - fx, dy = y - fy;
      int bx = (int)fx, by = (int)fy;
      float l0 = dots[nl][36 + k*2], l1 = dots[nl][36 + k*2 + 1];
      float mmax = fmaxf(l0, l1);
      float e0 = __expf(l0 - mmax), e1 = __expf(l1 - mmax);
      float pwv = (p ? e1 : e0) / (e0 + e1);
      float mwv = 1.f / (1.f + __expf(-dots[nl][54 + k]));
      float wb  = pwv * mwv;
      const int* imap = id_map + roi_ids[n] * 4096;
      int base = ((n * 9 + k) * 2 + p) * 4;
      #pragma unroll
      for (int g = 0; g < 4; ++g) {
        int gx = g & 1, gy = g >> 1;
        int cx = bx + gx, cy = by + gy;
        bool pad = ((cx | cy) < 0) | (cx >= 64) | (cy >= 64);
        int cxc = min(max(cx, 0), 63), cyc = min(max(cy, 0), 63);
        int gid = pad ? 12000 : imap[cyc * 64 + cxc];
        float f1 = gx ? dx : dy;
        float f2 = gy ? (1.f - dx) : (1.f - dy);
        gids[base + g] = gid;
        wts[base + g]  = wb * f1 * f2;
      }
    }
  }
}

// ---------------------------------------------------------------------------
// K1: gather-combine -> sampled bf16 (8000 x 2304)
// wave per row n; lane owns 4 channels; next tap's gid/w prefetched under FMA
// ---------------------------------------------------------------------------
__global__ __launch_bounds__(256) void gather_kernel(
    const unsigned short* __restrict__ tab,
    const int* __restrict__ gids, const float* __restrict__ wts,
    unsigned short* __restrict__ sampled)
{
  const int lane = threadIdx.x & 63;
  const int wv   = threadIdx.x >> 6;
  const int n    = blockIdx.x * 4 + wv;
  const int c    = lane * 4;
  const long jb  = (long)n * 72;

  int gid[8]; float w[8];
  #pragma unroll
  for (int j = 0; j < 8; ++j) { gid[j] = gids[jb + j]; w[j] = wts[jb + j]; }

  #pragma unroll
  for (int k = 0; k < 9; ++k) {
    ushort4 tv[8];
    #pragma unroll
    for (int j = 0; j < 8; ++j)
      tv[j] = *(const ushort4*)(tab + (long)gid[j] * 256 + c);
    int ngid[8]; float nw[8];
    if (k < 8) {
      #pragma unroll
      for (int j = 0; j < 8; ++j) {
        ngid[j] = gids[jb + (k + 1) * 8 + j];
        nw[j]   = wts[jb + (k + 1) * 8 + j];
      }
    }
    float a0 = 0.f, a1 = 0.f, a2 = 0.f, a3 = 0.f;
    #pragma unroll
    for (int j = 0; j < 8; ++j) {
      a0 += w[j] * b2f(tv[j].x); a1 += w[j] * b2f(tv[j].y);
      a2 += w[j] * b2f(tv[j].z); a3 += w[j] * b2f(tv[j].w);
    }
    *(ushort4*)(sampled + ((long)n * 2304 + k * 256 + c)) =
        make_ushort4(f2b(a0), f2b(a1), f2b(a2), f2b(a3));
    if (k < 8) {
      #pragma unroll
      for (int j = 0; j < 8; ++j) { gid[j] = ngid[j]; w[j] = nw[j]; }
    }
  }
}

// ---------------------------------------------------------------------------
// K2: out = sampled(8000x2304) @ weight^T(2304x256) + bias   (bf16 MFMA)
// 64x64 tile, BK=64, 4 waves (2x2). 1D grid 500, bijective XCD-chunk swizzle
// (nwg=500,q=62,r=4) with the 4 N-siblings of an S-strip contiguous -> same
// XCD L2 serves the 3 strip re-reads.
// ---------------------------------------------------------------------------
__global__ __launch_bounds__(256) void gemm_kernel(
    const unsigned short* __restrict__ S,
    const unsigned short* __restrict__ W,
    const float* __restrict__ bias,
    float* __restrict__ out)
{
  __shared__ __align__(16) unsigned short As[64][72];
  __shared__ __align__(16) unsigned short Bs[64][72];

  const int orig = blockIdx.x;
  const int xcd  = orig & 7;
  const int wgid = (xcd < 4 ? xcd * 63 : 4 * 63 + (xcd - 4) * 62) + (orig >> 3);
  const int m0 = (wgid >> 2) * 64;
  const int n0 = (wgid & 3) * 64;

  const int t    = threadIdx.x;
  const int lane = t & 63;
  const int wv   = t >> 6;
  const int wr   = wv >> 1, wc = wv & 1;

  f32x4 acc[2][2] = {};

  const int srow = t >> 3;   // 0..31
  const int schk = t & 7;    // 0..7

  for (int kt = 0; kt < 36; ++kt) {
    const int k0 = kt * 64;
    const uint4 ra0 = *(const uint4*)(S + (long)(m0 + srow)      * 2304 + k0 + schk * 8);
    const uint4 ra1 = *(const uint4*)(S + (long)(m0 + srow + 32) * 2304 + k0 + schk * 8);
    const uint4 rb0 = *(const uint4*)(W + (long)(n0 + srow)      * 2304 + k0 + schk * 8);
    const uint4 rb1 = *(const uint4*)(W + (long)(n0 + srow + 32) * 2304 + k0 + schk * 8);
    __syncthreads();
    *(uint4*)&As[srow][schk * 8]      = ra0;
    *(uint4*)&As[srow + 32][schk * 8] = ra1;
    *(uint4*)&Bs[srow][schk * 8]      = rb0;
    *(uint4*)&Bs[srow + 32][schk * 8] = rb1;
    __syncthreads();
    #pragma unroll
    for (int kc = 0; kc < 2; ++kc) {
      const int kk = kc * 32 + (lane >> 4) * 8;
      short8 af[2], bf[2];
      af[0] = *(const short8*)&As[wr * 32 + (lane & 15)][kk];
      af[1] = *(const short8*)&As[wr * 32 + 16 + (lane & 15)][kk];
      bf[0] = *(const short8*)&Bs[wc * 32 + (lane & 15)][kk];
      bf[1] = *(const short8*)&Bs[wc * 32 + 16 + (lane & 15)][kk];
      #pragma unroll
      for (int i = 0; i < 2; ++i)
        #pragma unroll
        for (int j = 0; j < 2; ++j)
          acc[i][j] = __builtin_amdgcn_mfma_f32_16x16x32_bf16(af[i], bf[j], acc[i][j], 0, 0, 0);
    }
  }

  #pragma unroll
  for (int i = 0; i < 2; ++i) {
    const int row = m0 + wr * 32 + i * 16 + (lane >> 4) * 4;
    #pragma unroll
    for (int j = 0; j < 2; ++j) {
      const int col = n0 + wc * 32 + j * 16 + (lane & 15);
      const float bs = bias[col];
      #pragma unroll
      for (int r = 0; r < 4; ++r)
        out[(long)(row + r) * 256 + col] = acc[i][j][r] + bs;
    }
  }
}

// ---------------------------------------------------------------------------
extern "C" void kernel_launch(void* const* d_in, const int* in_sizes, int n_in,
                              void* d_out, int out_size, void* d_ws, size_t ws_size,
                              hipStream_t stream)
{
  const float* core   = (const float*)d_in[0];
  const float* aux    = (const float*)d_in[1];
  const float* off_w  = (const float*)d_in[2];
  const float* off_b  = (const float*)d_in[3];
  const float* pw_w   = (const float*)d_in[4];
  const float* pw_b   = (const float*)d_in[5];
  const float* mw_w   = (const float*)d_in[6];
  const float* mw_b   = (const float*)d_in[7];
  const float* wgt    = (const float*)d_in[8];
  const float* bias   = (const float*)d_in[9];
  const int* id_map   = (const int*)d_in[10];
  const int* roi_ids  = (const int*)d_in[11];
  const int* pos_ids  = (const int*)d_in[12];
  char* ws = (char*)d_ws;

  unsigned short* tab     = (unsigned short*)(ws);              // 12001*256*2
  unsigned short* wB      = (unsigned short*)(ws + 6144512);    // 256*2304*2
  int*            gd      = (int*)           (ws + 7324160);    // 8000*72*4
  float*          wt      = (float*)         (ws + 9628160);    // 8000*72*4
  unsigned short* sampled = (unsigned short*)(ws + 11932160);   // 8000*2304*2
  float* out = (float*)d_out;

  hipLaunchKernelGGL(setup_kernel, dim3(3827), dim3(256), 0, stream,
                     core, aux, wgt, off_w, off_b, pw_w, pw_b, mw_w, mw_b,
                     id_map, roi_ids, pos_ids, tab, wB, gd, wt);
  hipLaunchKernelGGL(gather_kernel, dim3(2000), dim3(256), 0, stream,
                     tab, gd, wt, sampled);
  hipLaunchKernelGGL(gemm_kernel, dim3(500), dim3(256), 0, stream,
                     sampled, wB, bias, out);
}

// Round 8
// 180.752 us; speedup vs baseline: 1.3932x; 1.2422x over previous
//
#include <hip/hip_runtime.h>

typedef __attribute__((ext_vector_type(8))) short short8;
typedef __attribute__((ext_vector_type(4))) float f32x4;

static __device__ __forceinline__ unsigned short f2b(float f) {
  union { float f; unsigned int u; } v; v.f = f;
  unsigned int u = v.u;
  unsigned int r = (u + 0x7FFFu + ((u >> 16) & 1u)) >> 16;
  return (unsigned short)r;
}
static __device__ __forceinline__ float b2f(unsigned short u) {
  union { unsigned int u; float f; } v; v.u = ((unsigned int)u) << 16;
  return v.f;
}

// ---------------------------------------------------------------------------
// K0: prep. blocks 0..3576: cast feature table (core|aux|zero) + weight to
// bf16. block 3577: build Wtq (f32 transposed proj weights, [64 chunks][64
// dots] float4) + packed bias bb[64]. Proj weights stay f32: dots feed
// floor(), bf16 error would flip floors (discontinuous bilinear weights).
// ---------------------------------------------------------------------------
__global__ __launch_bounds__(256) void setup_kernel(
    const float* __restrict__ core, const float* __restrict__ aux,
    const float* __restrict__ wgt,
    const float* __restrict__ off_w, const float* __restrict__ off_b,
    const float* __restrict__ pw_w,  const float* __restrict__ pw_b,
    const float* __restrict__ mw_w,  const float* __restrict__ mw_b,
    unsigned short* __restrict__ tab, unsigned short* __restrict__ wB,
    float* __restrict__ Wtq, float* __restrict__ bb)
{
  if (blockIdx.x < 3577) {
    const long TAB = 12001L * 256;
    const long WN  = 256L * 2304;
    long i = ((long)blockIdx.x * 256 + threadIdx.x) * 4;
    float4 v;
    unsigned short* dst;
    if (i < TAB) {
      long row = i >> 8;
      if (row < 8000)        v = *(const float4*)(core + i);
      else if (row < 12000)  v = *(const float4*)(aux + (i - 8000L * 256));
      else                   v = make_float4(0.f, 0.f, 0.f, 0.f);
      dst = tab + i;
    } else {
      long j = i - TAB;
      if (j >= WN) return;
      v = *(const float4*)(wgt + j);
      dst = wB + j;
    }
    *(ushort4*)dst = make_ushort4(f2b(v.x), f2b(v.y), f2b(v.z), f2b(v.w));
    return;
  }
  // ---- transpose proj weights: Wtq[i][d] = {W_all[d][4i..4i+3]}
  for (int e = threadIdx.x; e < 16384; e += 256) {
    int i = e >> 8;
    int d = (e >> 2) & 63;
    int j = e & 3;
    int c = i * 4 + j;
    float v;
    if (d < 36)      v = off_w[d * 256 + c];
    else if (d < 54) v = pw_w[(d - 36) * 256 + c];
    else if (d < 63) v = mw_w[(d - 54) * 256 + c];
    else             v = 0.f;
    Wtq[(i * 64 + d) * 4 + j] = v;
  }
  if (threadIdx.x < 64) {
    int d = threadIdx.x;
    float b;
    if (d < 36)      b = off_b[d];
    else if (d < 54) b = pw_b[d - 36];
    else if (d < 63) b = mw_b[d - 54];
    else             b = 0.f;
    bb[d] = b;
  }
}

// ---------------------------------------------------------------------------
// K1: proj v2. 500 blocks x 256 thr (4 waves x 4 rows = 16 rows/block).
// Lane d computes dot d for its wave's 4 rows; Wtq read is coalesced b128,
// x read is wave-uniform (broadcast). Then 288 (row,k,p) tasks -> gids/wts.
// Reference's NON-standard bilinear: w[g] = delta[x_ids[g]]*(1-delta)[y_ids[g]],
// x_ids=[1,0,1,0], y_ids=[1,1,0,0] -> f1 = gx?dx:dy ; f2 = gy?(1-dx):(1-dy)
// ---------------------------------------------------------------------------
__global__ __launch_bounds__(256) void proj_kernel(
    const float* __restrict__ core,
    const float* __restrict__ Wtq, const float* __restrict__ bb,
    const int* __restrict__ id_map, const int* __restrict__ roi_ids,
    const int* __restrict__ pos_ids,
    int* __restrict__ gids, float* __restrict__ wts)
{
  __shared__ float dots[16][64];
  const int tid  = threadIdx.x;
  const int lane = tid & 63;
  const int wv   = tid >> 6;
  const int nbase = blockIdx.x * 16 + wv * 4;

  float acc0 = 0.f, acc1 = 0.f, acc2 = 0.f, acc3 = 0.f;
  const float4* W4 = (const float4*)Wtq;
  #pragma unroll 4
  for (int i = 0; i < 64; ++i) {
    const float4 w = W4[i * 64 + lane];
    const float4 x0 = *(const float4*)(core + (long)(nbase + 0) * 256 + i * 4);
    const float4 x1 = *(const float4*)(core + (long)(nbase + 1) * 256 + i * 4);
    const float4 x2 = *(const float4*)(core + (long)(nbase + 2) * 256 + i * 4);
    const float4 x3 = *(const float4*)(core + (long)(nbase + 3) * 256 + i * 4);
    acc0 += w.x * x0.x + w.y * x0.y + w.z * x0.z + w.w * x0.w;
    acc1 += w.x * x1.x + w.y * x1.y + w.z * x1.z + w.w * x1.w;
    acc2 += w.x * x2.x + w.y * x2.y + w.z * x2.z + w.w * x2.w;
    acc3 += w.x * x3.x + w.y * x3.y + w.z * x3.z + w.w * x3.w;
  }
  const float b = bb[lane];
  dots[wv * 4 + 0][lane] = acc0 + b;
  dots[wv * 4 + 1][lane] = acc1 + b;
  dots[wv * 4 + 2][lane] = acc2 + b;
  dots[wv * 4 + 3][lane] = acc3 + b;
  __syncthreads();

  #pragma unroll
  for (int round = 0; round < 2; ++round) {
    int task = round * 256 + tid;
    if (task < 288) {
      int nl = task / 18;
      int kp = task - nl * 18;
      int k = kp >> 1, p = kp & 1;
      int n = blockIdx.x * 16 + nl;
      float x = dots[nl][k*4 + p*2 + 0] + (float)pos_ids[n*2 + 0];
      float y = dots[nl][k*4 + p*2 + 1] + (float)pos_ids[n*2 + 1];
      float fx = floorf(x), fy = floorf(y);
      float dx = x - fx, dy = y - fy;
      int bx = (int)fx, by = (int)fy;
      float l0 = dots[nl][36 + k*2], l1 = dots[nl][36 + k*2 + 1];
      float mmax = fmaxf(l0, l1);
      float e0 = __expf(l0 - mmax), e1 = __expf(l1 - mmax);
      float pwv = (p ? e1 : e0) / (e0 + e1);
      float mwv = 1.f / (1.f + __expf(-dots[nl][54 + k]));
      float wb  = pwv * mwv;
      const int* imap = id_map + roi_ids[n] * 4096;
      int base = ((n * 9 + k) * 2 + p) * 4;
      #pragma unroll
      for (int g = 0; g < 4; ++g) {
        int gx = g & 1, gy = g >> 1;
        int cx = bx + gx, cy = by + gy;
        bool pad = ((cx | cy) < 0) | (cx >= 64) | (cy >= 64);
        int cxc = min(max(cx, 0), 63), cyc = min(max(cy, 0), 63);
        int gid = pad ? 12000 : imap[cyc * 64 + cxc];
        float f1 = gx ? dx : dy;
        float f2 = gy ? (1.f - dx) : (1.f - dy);
        gids[base + g] = gid;
        wts[base + g]  = wb * f1 * f2;
      }
    }
  }
}

// ---------------------------------------------------------------------------
// K2: gather-combine -> sampled bf16 (8000 x 2304)
// wave per row n; lane owns 4 channels; next tap's gid/w prefetched under FMA
// ---------------------------------------------------------------------------
__global__ __launch_bounds__(256) void gather_kernel(
    const unsigned short* __restrict__ tab,
    const int* __restrict__ gids, const float* __restrict__ wts,
    unsigned short* __restrict__ sampled)
{
  const int lane = threadIdx.x & 63;
  const int wv   = threadIdx.x >> 6;
  const int n    = blockIdx.x * 4 + wv;
  const int c    = lane * 4;
  const long jb  = (long)n * 72;

  int gid[8]; float w[8];
  #pragma unroll
  for (int j = 0; j < 8; ++j) { gid[j] = gids[jb + j]; w[j] = wts[jb + j]; }

  #pragma unroll
  for (int k = 0; k < 9; ++k) {
    ushort4 tv[8];
    #pragma unroll
    for (int j = 0; j < 8; ++j)
      tv[j] = *(const ushort4*)(tab + (long)gid[j] * 256 + c);
    int ngid[8]; float nw[8];
    if (k < 8) {
      #pragma unroll
      for (int j = 0; j < 8; ++j) {
        ngid[j] = gids[jb + (k + 1) * 8 + j];
        nw[j]   = wts[jb + (k + 1) * 8 + j];
      }
    }
    float a0 = 0.f, a1 = 0.f, a2 = 0.f, a3 = 0.f;
    #pragma unroll
    for (int j = 0; j < 8; ++j) {
      a0 += w[j] * b2f(tv[j].x); a1 += w[j] * b2f(tv[j].y);
      a2 += w[j] * b2f(tv[j].z); a3 += w[j] * b2f(tv[j].w);
    }
    *(ushort4*)(sampled + ((long)n * 2304 + k * 256 + c)) =
        make_ushort4(f2b(a0), f2b(a1), f2b(a2), f2b(a3));
    if (k < 8) {
      #pragma unroll
      for (int j = 0; j < 8; ++j) { gid[j] = ngid[j]; w[j] = nw[j]; }
    }
  }
}

// ---------------------------------------------------------------------------
// K3: out = sampled(8000x2304) @ weight^T(2304x256) + bias   (bf16 MFMA)
// 64x64 tile, BK=64, 4 waves (2x2). 1D grid 500, bijective XCD-chunk swizzle
// (nwg=500,q=62,r=4) with the 4 N-siblings of an S-strip contiguous.
// ---------------------------------------------------------------------------
__global__ __launch_bounds__(256) void gemm_kernel(
    const unsigned short* __restrict__ S,
    const unsigned short* __restrict__ W,
    const float* __restrict__ bias,
    float* __restrict__ out)
{
  __shared__ __align__(16) unsigned short As[64][72];
  __shared__ __align__(16) unsigned short Bs[64][72];

  const int orig = blockIdx.x;
  const int xcd  = orig & 7;
  const int wgid = (xcd < 4 ? xcd * 63 : 4 * 63 + (xcd - 4) * 62) + (orig >> 3);
  const int m0 = (wgid >> 2) * 64;
  const int n0 = (wgid & 3) * 64;

  const int t    = threadIdx.x;
  const int lane = t & 63;
  const int wv   = t >> 6;
  const int wr   = wv >> 1, wc = wv & 1;

  f32x4 acc[2][2] = {};

  const int srow = t >> 3;   // 0..31
  const int schk = t & 7;    // 0..7

  for (int kt = 0; kt < 36; ++kt) {
    const int k0 = kt * 64;
    const uint4 ra0 = *(const uint4*)(S + (long)(m0 + srow)      * 2304 + k0 + schk * 8);
    const uint4 ra1 = *(const uint4*)(S + (long)(m0 + srow + 32) * 2304 + k0 + schk * 8);
    const uint4 rb0 = *(const uint4*)(W + (long)(n0 + srow)      * 2304 + k0 + schk * 8);
    const uint4 rb1 = *(const uint4*)(W + (long)(n0 + srow + 32) * 2304 + k0 + schk * 8);
    __syncthreads();
    *(uint4*)&As[srow][schk * 8]      = ra0;
    *(uint4*)&As[srow + 32][schk * 8] = ra1;
    *(uint4*)&Bs[srow][schk * 8]      = rb0;
    *(uint4*)&Bs[srow + 32][schk * 8] = rb1;
    __syncthreads();
    #pragma unroll
    for (int kc = 0; kc < 2; ++kc) {
      const int kk = kc * 32 + (lane >> 4) * 8;
      short8 af[2], bf[2];
      af[0] = *(const short8*)&As[wr * 32 + (lane & 15)][kk];
      af[1] = *(const short8*)&As[wr * 32 + 16 + (lane & 15)][kk];
      bf[0] = *(const short8*)&Bs[wc * 32 + (lane & 15)][kk];
      bf[1] = *(const short8*)&Bs[wc * 32 + 16 + (lane & 15)][kk];
      #pragma unroll
      for (int i = 0; i < 2; ++i)
        #pragma unroll
        for (int j = 0; j < 2; ++j)
          acc[i][j] = __builtin_amdgcn_mfma_f32_16x16x32_bf16(af[i], bf[j], acc[i][j], 0, 0, 0);
    }
  }

  #pragma unroll
  for (int i = 0; i < 2; ++i) {
    const int row = m0 + wr * 32 + i * 16 + (lane >> 4) * 4;
    #pragma unroll
    for (int j = 0; j < 2; ++j) {
      const int col = n0 + wc * 32 + j * 16 + (lane & 15);
      const float bs = bias[col];
      #pragma unroll
      for (int r = 0; r < 4; ++r)
        out[(long)(row + r) * 256 + col] = acc[i][j][r] + bs;
    }
  }
}

// ---------------------------------------------------------------------------
extern "C" void kernel_launch(void* const* d_in, const int* in_sizes, int n_in,
                              void* d_out, int out_size, void* d_ws, size_t ws_size,
                              hipStream_t stream)
{
  const float* core   = (const float*)d_in[0];
  const float* aux    = (const float*)d_in[1];
  const float* off_w  = (const float*)d_in[2];
  const float* off_b  = (const float*)d_in[3];
  const float* pw_w   = (const float*)d_in[4];
  const float* pw_b   = (const float*)d_in[5];
  const float* mw_w   = (const float*)d_in[6];
  const float* mw_b   = (const float*)d_in[7];
  const float* wgt    = (const float*)d_in[8];
  const float* bias   = (const float*)d_in[9];
  const int* id_map   = (const int*)d_in[10];
  const int* roi_ids  = (const int*)d_in[11];
  const int* pos_ids  = (const int*)d_in[12];
  char* ws = (char*)d_ws;

  unsigned short* tab     = (unsigned short*)(ws);              // 12001*256*2
  unsigned short* wB      = (unsigned short*)(ws + 6144512);    // 256*2304*2
  int*            gd      = (int*)           (ws + 7324160);    // 8000*72*4
  float*          wt      = (float*)         (ws + 9628160);    // 8000*72*4
  unsigned short* sampled = (unsigned short*)(ws + 11932160);   // 8000*2304*2
  float*          Wtq     = (float*)         (ws + 48796160);   // 64*64*4 f32
  float*          bb      = (float*)         (ws + 48861696);   // 64 f32
  float* out = (float*)d_out;

  hipLaunchKernelGGL(setup_kernel, dim3(3578), dim3(256), 0, stream,
                     core, aux, wgt, off_w, off_b, pw_w, pw_b, mw_w, mw_b,
                     tab, wB, Wtq, bb);
  hipLaunchKernelGGL(proj_kernel, dim3(500), dim3(256), 0, stream,
                     core, Wtq, bb, id_map, roi_ids, pos_ids, gd, wt);
  hipLaunchKernelGGL(gather_kernel, dim3(2000), dim3(256), 0, stream,
                     tab, gd, wt, sampled);
  hipLaunchKernelGGL(gemm_kernel, dim3(500), dim3(256), 0, stream,
                     sampled, wB, bias, out);
}